// Round 3
// baseline (98.946 us; speedup 1.0000x reference)
//
#include <hip/hip_runtime.h>
#include <hip/hip_bf16.h>
#include <float.h>
#include <math.h>

typedef short short8 __attribute__((ext_vector_type(8)));
typedef float f32x4  __attribute__((ext_vector_type(4)));

#define KEPS   1e-5f
#define DENOMC 1e-5f

__device__ __forceinline__ short f2bf(float x) {
    return __builtin_bit_cast(short, __float2bfloat16(x));
}

// unsorted top-10, slot 0 always holds the min (admission gate)
__device__ __forceinline__ void top10_insert(float (&lst)[10], float s) {
    if (s > lst[0]) {
        lst[0] = s;
        #pragma unroll
        for (int i = 1; i < 10; ++i) {
            float lo = fminf(lst[0], lst[i]);
            float hi = fmaxf(lst[0], lst[i]);
            lst[0] = lo; lst[i] = hi;
        }
    }
}

// ---------------------------------------------------------------------------
// Kernel 1: stream memory once with depth-1 register prefetch.
// Role-swapped MFMA: A = -2*q (queries), B = memory rows, C = splat(m2_c).
// acc[r] of MFMA h = m2_c - 2*q_{16h+4g+r} . m_{w*16+c}  (score; +q2 later).
// Per-lane top-1 per query (16 streams of ~24 rows each per (query,block)).
// ---------------------------------------------------------------------------
__global__ __launch_bounds__(256, 5) void ep_main(
    const float* __restrict__ q, const float* __restrict__ mem,
    float* __restrict__ part_top,    // [64][nb][10]
    float* __restrict__ part_sums,   // [33][nb]  (colsum rows 0..31, sumsq row 32)
    int nb, int ntiles)
{
    const int tid  = threadIdx.x;
    const int lane = tid & 63;
    const int wave = tid >> 6;
    const int g    = lane >> 4;   // k-chunk group (0..3), k = 8g..8g+7
    const int c    = lane & 15;   // memrow-within-wave-subtile
    const int bid  = blockIdx.x;

    // A fragments (M x K = 16 x 32): lane holds -2*q[16h + c][8g .. 8g+8)
    short8 qfrag[4];
    #pragma unroll
    for (int h = 0; h < 4; ++h) {
        const float* qp = q + (h * 16 + c) * 32 + g * 8;
        float4 w0 = *(const float4*)qp;
        float4 w1 = *(const float4*)(qp + 4);
        short8 f;
        f[0]=f2bf(-2.f*w0.x); f[1]=f2bf(-2.f*w0.y); f[2]=f2bf(-2.f*w0.z); f[3]=f2bf(-2.f*w0.w);
        f[4]=f2bf(-2.f*w1.x); f[5]=f2bf(-2.f*w1.y); f[6]=f2bf(-2.f*w1.z); f[7]=f2bf(-2.f*w1.w);
        qfrag[h] = f;
    }

    float t1[16];                 // top-1 per query 16h+4g+r  (index h*4+r)
    #pragma unroll
    for (int i = 0; i < 16; ++i) t1[i] = -FLT_MAX;
    float cs[8];
    #pragma unroll
    for (int r = 0; r < 8; ++r) cs[r] = 0.f;
    float sumsq = 0.f;

    const size_t lane_off = (size_t)(wave * 16 + c) * 32 + (size_t)(g * 8);
    const size_t step     = (size_t)nb * 2048;

    auto process = [&](float4 v0, float4 v1) {
        float ps;
        ps = v0.x * v0.x;
        ps = fmaf(v0.y, v0.y, ps);
        ps = fmaf(v0.z, v0.z, ps);
        ps = fmaf(v0.w, v0.w, ps);
        ps = fmaf(v1.x, v1.x, ps);
        ps = fmaf(v1.y, v1.y, ps);
        ps = fmaf(v1.z, v1.z, ps);
        ps = fmaf(v1.w, v1.w, ps);
        sumsq += ps;
        cs[0] += v0.x; cs[1] += v0.y; cs[2] += v0.z; cs[3] += v0.w;
        cs[4] += v1.x; cs[5] += v1.y; cs[6] += v1.z; cs[7] += v1.w;

        // full row norm of row c: reduce ps across the 4 k-groups
        float m2 = ps + __shfl_xor(ps, 16, 64);
        m2 = m2 + __shfl_xor(m2, 32, 64);
        f32x4 mi = {m2, m2, m2, m2};

        // B fragment (K x N = 32 x 16): lane holds memrow(c)[8g .. 8g+8)
        short8 mf;
        mf[0]=f2bf(v0.x); mf[1]=f2bf(v0.y); mf[2]=f2bf(v0.z); mf[3]=f2bf(v0.w);
        mf[4]=f2bf(v1.x); mf[5]=f2bf(v1.y); mf[6]=f2bf(v1.z); mf[7]=f2bf(v1.w);

        #pragma unroll
        for (int h = 0; h < 4; ++h) {
            f32x4 acc = __builtin_amdgcn_mfma_f32_16x16x32_bf16(qfrag[h], mf, mi, 0, 0, 0);
            t1[h*4+0] = fmaxf(t1[h*4+0], acc[0]);
            t1[h*4+1] = fmaxf(t1[h*4+1], acc[1]);
            t1[h*4+2] = fmaxf(t1[h*4+2], acc[2]);
            t1[h*4+3] = fmaxf(t1[h*4+3], acc[3]);
        }
    };

    // depth-1 software pipeline
    const float* p = mem + (size_t)bid * 2048 + lane_off;
    float4 v0 = *(const float4*)p;
    float4 v1 = *(const float4*)(p + 4);
    p += step;
    for (int t = bid + nb; t < ntiles; t += nb) {
        float4 w0 = *(const float4*)p;
        float4 w1 = *(const float4*)(p + 4);
        p += step;
        process(v0, v1);
        v0 = w0; v1 = w1;
    }
    process(v0, v1);

    // ---- block-level merge ----
    __shared__ float ltop[64][65];   // [query][stream=w*16+c], padded
    __shared__ float red[4][4][8];
    __shared__ float ssred[4];

    const int col = wave * 16 + c;
    #pragma unroll
    for (int h = 0; h < 4; ++h) {
        #pragma unroll
        for (int r = 0; r < 4; ++r)
            ltop[h * 16 + g * 4 + r][col] = t1[h * 4 + r];
    }

    #pragma unroll
    for (int r = 0; r < 8; ++r) {
        float v = cs[r];
        v += __shfl_xor(v, 1, 64);
        v += __shfl_xor(v, 2, 64);
        v += __shfl_xor(v, 4, 64);
        v += __shfl_xor(v, 8, 64);
        cs[r] = v;
    }
    float ssv = sumsq;
    ssv += __shfl_xor(ssv, 1, 64);
    ssv += __shfl_xor(ssv, 2, 64);
    ssv += __shfl_xor(ssv, 4, 64);
    ssv += __shfl_xor(ssv, 8, 64);
    ssv += __shfl_xor(ssv, 16, 64);
    ssv += __shfl_xor(ssv, 32, 64);
    if (c == 0) {
        #pragma unroll
        for (int r = 0; r < 8; ++r) red[wave][g][r] = cs[r];
    }
    if (lane == 0) ssred[wave] = ssv;
    __syncthreads();

    if (tid < 32) {
        float a = red[0][tid >> 3][tid & 7] + red[1][tid >> 3][tid & 7]
                + red[2][tid >> 3][tid & 7] + red[3][tid >> 3][tid & 7];
        part_sums[(size_t)tid * nb + bid] = a;
    } else if (tid == 32) {
        part_sums[(size_t)32 * nb + bid] = ssred[0] + ssred[1] + ssred[2] + ssred[3];
    }

    if (tid < 64) {
        float lst[10];
        #pragma unroll
        for (int i = 0; i < 10; ++i) lst[i] = -FLT_MAX;
        #pragma unroll 4
        for (int s2 = 0; s2 < 64; ++s2) top10_insert(lst, ltop[tid][s2]);
        #pragma unroll
        for (int i = 0; i < 10; ++i)
            part_top[((size_t)tid * nb + bid) * 10 + i] = lst[i];
    }
}

// ---------------------------------------------------------------------------
// Kernel 2 (fused tail): 64 blocks, one per query. Each block redundantly
// reduces part_sums -> closed-form global mean (coalesced [33][nb] layout,
// L2-hot), merges its query's nb block-top-10s, and emits the reward.
// ---------------------------------------------------------------------------
__global__ __launch_bounds__(256) void ep_tail(
    const float* __restrict__ q, const float* __restrict__ part_top,
    const float* __restrict__ part_sums, float* __restrict__ out,
    int nb, int Mrows)
{
    const int b    = blockIdx.x;
    const int tid  = threadIdx.x;
    const int lane = tid & 63;
    const int wave = tid >> 6;

    __shared__ float smem[256 * 33];    // 33.8 KB, reused across phases
    __shared__ float colsum_a[33];
    __shared__ float w4[4];
    __shared__ float mean_s, q2_s;

    // q2 of this block's query
    if (tid < 64) {
        float x = (tid < 32) ? q[b * 32 + tid] : 0.f;
        float a = x * x;
        a += __shfl_xor(a, 1, 64);
        a += __shfl_xor(a, 2, 64);
        a += __shfl_xor(a, 4, 64);
        a += __shfl_xor(a, 8, 64);
        a += __shfl_xor(a, 16, 64);
        if (tid == 0) q2_s = a;
    }

    // sum of squares of all query elements (2048 elems, 8 per thread)
    float a2 = 0.f;
    #pragma unroll
    for (int e = 0; e < 8; ++e) {
        float x = q[tid * 8 + e];
        a2 = fmaf(x, x, a2);
    }
    a2 += __shfl_xor(a2, 1, 64);
    a2 += __shfl_xor(a2, 2, 64);
    a2 += __shfl_xor(a2, 4, 64);
    a2 += __shfl_xor(a2, 8, 64);
    a2 += __shfl_xor(a2, 16, 64);
    a2 += __shfl_xor(a2, 32, 64);
    if (lane == 0) w4[wave] = a2;

    // phase A: reduce the 33 partial-sum rows (coalesced over i)
    float acc[33];
    #pragma unroll
    for (int c2 = 0; c2 < 33; ++c2) acc[c2] = 0.f;
    for (int i = tid; i < nb; i += 256) {
        #pragma unroll
        for (int c2 = 0; c2 < 33; ++c2) acc[c2] += part_sums[(size_t)c2 * nb + i];
    }
    #pragma unroll
    for (int c2 = 0; c2 < 33; ++c2) smem[tid * 33 + c2] = acc[c2];
    __syncthreads();
    if (tid < 33) {
        float a = 0.f;
        #pragma unroll 16
        for (int j = 0; j < 256; ++j) a += smem[j * 33 + tid];
        colsum_a[tid] = a;
    }
    __syncthreads();

    if (tid < 32) {
        float qs = 0.f;
        #pragma unroll 8
        for (int bb = 0; bb < 64; ++bb) qs += q[bb * 32 + tid];
        float dq = qs * colsum_a[tid];
        dq += __shfl_xor(dq, 1, 64);
        dq += __shfl_xor(dq, 2, 64);
        dq += __shfl_xor(dq, 4, 64);
        dq += __shfl_xor(dq, 8, 64);
        dq += __shfl_xor(dq, 16, 64);
        if (tid == 0) {
            double q2sum = (double)w4[0] + (double)w4[1] + (double)w4[2] + (double)w4[3];
            double sumsq = (double)colsum_a[32];
            double Md    = (double)Mrows;
            mean_s = (float)((Md * q2sum + 64.0 * sumsq - 2.0 * (double)dq) / (64.0 * Md));
        }
    }
    __syncthreads();

    // phase B: merge this query's nb candidate lists (contiguous, L2-hot)
    float lst[10];
    #pragma unroll
    for (int i = 0; i < 10; ++i) lst[i] = -FLT_MAX;
    const float* pt = part_top + (size_t)b * nb * 10;
    for (int i = tid; i < nb; i += 256) {
        const float* pp = pt + (size_t)i * 10;
        #pragma unroll
        for (int r = 0; r < 10; ++r) top10_insert(lst, pp[r]);
    }
    #pragma unroll
    for (int r = 0; r < 10; ++r) smem[tid * 10 + r] = lst[r];
    __syncthreads();

    if (tid < 32) {
        float m[10];
        #pragma unroll
        for (int i = 0; i < 10; ++i) m[i] = -FLT_MAX;
        for (int j2 = 0; j2 < 8; ++j2) {
            #pragma unroll
            for (int r = 0; r < 10; ++r) top10_insert(m, smem[(tid * 8 + j2) * 10 + r]);
        }
        #pragma unroll
        for (int r = 0; r < 10; ++r) smem[2560 + tid * 10 + r] = m[r];
    }
    __syncthreads();

    if (tid == 0) {
        float m[10];
        #pragma unroll
        for (int i = 0; i < 10; ++i) m[i] = -FLT_MAX;
        for (int j2 = 0; j2 < 32; ++j2) {
            #pragma unroll
            for (int r = 0; r < 10; ++r) top10_insert(m, smem[2560 + j2 * 10 + r]);
        }
        const float mean = mean_s;
        const float q2b  = q2_s;
        float sum = 0.f;
        #pragma unroll
        for (int r = 0; r < 10; ++r) {
            float sq = m[r] + q2b;        // score + |q|^2 = squared distance
            sq = fmaxf(sq, 0.f);
            sum += KEPS / (sq / mean + KEPS);
        }
        out[b] = 1.0f / sqrtf(sum + DENOMC);
    }
}

// ---------------------------------------------------------------------------
extern "C" void kernel_launch(void* const* d_in, const int* in_sizes, int n_in,
                              void* d_out, int out_size, void* d_ws, size_t ws_size,
                              hipStream_t stream)
{
    const float* q   = (const float*)d_in[0];
    const float* mem = (const float*)d_in[1];
    float* out = (float*)d_out;

    const int Mrows  = in_sizes[1] / 32;   // 2,000,000
    const int ntiles = Mrows / 64;         // 31,250

    // 256 CUs x 5 resident blocks -> one clean residency round
    int nb = 1280;
    while (nb > 64 && ((size_t)nb * 673 + 64) * sizeof(float) > ws_size) nb >>= 1;
    if (nb > ntiles) nb = ntiles;

    float* part_top  = (float*)d_ws;                         // [64][nb][10]
    float* part_sums = part_top + (size_t)64 * nb * 10;      // [33][nb]

    ep_main<<<dim3(nb), dim3(256), 0, stream>>>(q, mem, part_top, part_sums, nb, ntiles);
    ep_tail<<<dim3(64), dim3(256), 0, stream>>>(q, part_top, part_sums, out, nb, Mrows);
}

// Round 4
// 97.924 us; speedup vs baseline: 1.0104x; 1.0104x over previous
//
#include <hip/hip_runtime.h>
#include <hip/hip_bf16.h>
#include <float.h>
#include <math.h>

typedef short short8 __attribute__((ext_vector_type(8)));
typedef float f32x4  __attribute__((ext_vector_type(4)));

#define KEPS   1e-5f
#define DENOMC 1e-5f

__device__ __forceinline__ short f2bf(float x) {
    return __builtin_bit_cast(short, __float2bfloat16(x));
}

// async global->LDS, 16 B per lane, per-lane global src, wave-uniform LDS dest
__device__ __forceinline__ void gload_lds16(const void* g, void* l) {
    __builtin_amdgcn_global_load_lds(
        (const __attribute__((address_space(1))) void*)g,
        (__attribute__((address_space(3))) void*)l,
        16, 0, 0);
}

// unsorted top-10, slot 0 always holds the min (admission gate)
__device__ __forceinline__ void top10_insert(float (&lst)[10], float s) {
    if (s > lst[0]) {
        lst[0] = s;
        #pragma unroll
        for (int i = 1; i < 10; ++i) {
            float lo = fminf(lst[0], lst[i]);
            float hi = fmaxf(lst[0], lst[i]);
            lst[0] = lo; lst[i] = hi;
        }
    }
}

// ---------------------------------------------------------------------------
// Kernel 1: stream memory once, staged through double-buffered LDS via
// global_load_lds (fully coalesced 1-KB-per-wave stage instructions).
// 2-bit XOR swizzle (granule ^= (c&3)<<1) applied on the global SOURCE
// (involution) so the linear LDS write + swizzled LDS read compose to
// identity; read-side bank conflict drops 16-way -> 4-way.
// Role-swapped MFMA: A = -2*q, B = memory rows, C = splat(row norm).
// ---------------------------------------------------------------------------
__global__ __launch_bounds__(256, 5) void ep_main(
    const float* __restrict__ q, const float* __restrict__ mem,
    float* __restrict__ part_top,    // [64][nb][10]
    float* __restrict__ part_sums,   // [33][nb]
    int nb, int ntiles)
{
    // 16 KB staging (2 x 8 KB) + merge-phase ltop overlays the same memory
    __shared__ float smem[4224];     // >= max(2*2048, 64*65) floats
    __shared__ float red[4][4][8];
    __shared__ float ssred[4];

    const int tid  = threadIdx.x;
    const int lane = tid & 63;
    const int wave = tid >> 6;
    const int g    = lane >> 4;   // k-chunk group (0..3), k = 8g..8g+7
    const int c    = lane & 15;   // memrow-within-wave-subtile
    const int bid  = blockIdx.x;

    // A fragments (M x K = 16 x 32): lane holds -2*q[16h + c][8g .. 8g+8)
    short8 qfrag[4];
    #pragma unroll
    for (int h = 0; h < 4; ++h) {
        const float* qp = q + (h * 16 + c) * 32 + g * 8;
        f32x4 w0 = *(const f32x4*)qp;
        f32x4 w1 = *(const f32x4*)(qp + 4);
        short8 f;
        f[0]=f2bf(-2.f*w0[0]); f[1]=f2bf(-2.f*w0[1]); f[2]=f2bf(-2.f*w0[2]); f[3]=f2bf(-2.f*w0[3]);
        f[4]=f2bf(-2.f*w1[0]); f[5]=f2bf(-2.f*w1[1]); f[6]=f2bf(-2.f*w1[2]); f[7]=f2bf(-2.f*w1[3]);
        qfrag[h] = f;
    }

    float t1[16];                 // top-1 per query 16h+4g+r
    #pragma unroll
    for (int i = 0; i < 16; ++i) t1[i] = -FLT_MAX;
    float cs[8];
    #pragma unroll
    for (int r = 0; r < 8; ++r) cs[r] = 0.f;
    float sumsq = 0.f;

    // ---- staging addresses ----
    // thread T fills physical LDS granules T and T+256; source granule is
    // swizzled: S(z) = z ^ (((z>>3)&3)<<1)  (involution, bits 1-2 ^= bits 3-4)
    const int    swz  = ((tid >> 3) & 3) << 1;
    const size_t off0 = (size_t)(tid ^ swz) * 16;          // bytes in tile
    char* lds_d0[2], * lds_d1[2];
    #pragma unroll
    for (int b = 0; b < 2; ++b) {
        lds_d0[b] = (char*)smem + b * 8192 + wave * 1024;          // granules 64w..
        lds_d1[b] = (char*)smem + b * 8192 + 4096 + wave * 1024;   // +256 granules
    }
    // ---- fragment read address (physical, swizzled) ----
    const int    Y0    = wave * 128 + c * 8 + g * 2;       // logical granule (h=0)
    const size_t rdoff = (size_t)(Y0 ^ ((c & 3) << 1)) * 16;

    auto process = [&](const float* buf) {
        const f32x4* rp = (const f32x4*)((const char*)buf + rdoff);
        f32x4 v0 = rp[0];
        f32x4 v1 = rp[1];

        float ps;
        ps = v0[0] * v0[0];
        ps = fmaf(v0[1], v0[1], ps);
        ps = fmaf(v0[2], v0[2], ps);
        ps = fmaf(v0[3], v0[3], ps);
        ps = fmaf(v1[0], v1[0], ps);
        ps = fmaf(v1[1], v1[1], ps);
        ps = fmaf(v1[2], v1[2], ps);
        ps = fmaf(v1[3], v1[3], ps);
        sumsq += ps;
        cs[0] += v0[0]; cs[1] += v0[1]; cs[2] += v0[2]; cs[3] += v0[3];
        cs[4] += v1[0]; cs[5] += v1[1]; cs[6] += v1[2]; cs[7] += v1[3];

        // full row norm of row (wave*16+c): reduce ps across the 4 k-groups
        float m2 = ps + __shfl_xor(ps, 16, 64);
        m2 = m2 + __shfl_xor(m2, 32, 64);
        f32x4 mi = {m2, m2, m2, m2};

        // B fragment (K x N = 32 x 16): lane holds memrow[8g .. 8g+8)
        short8 mf;
        mf[0]=f2bf(v0[0]); mf[1]=f2bf(v0[1]); mf[2]=f2bf(v0[2]); mf[3]=f2bf(v0[3]);
        mf[4]=f2bf(v1[0]); mf[5]=f2bf(v1[1]); mf[6]=f2bf(v1[2]); mf[7]=f2bf(v1[3]);

        #pragma unroll
        for (int h = 0; h < 4; ++h) {
            f32x4 acc = __builtin_amdgcn_mfma_f32_16x16x32_bf16(qfrag[h], mf, mi, 0, 0, 0);
            t1[h*4+0] = fmaxf(t1[h*4+0], acc[0]);
            t1[h*4+1] = fmaxf(t1[h*4+1], acc[1]);
            t1[h*4+2] = fmaxf(t1[h*4+2], acc[2]);
            t1[h*4+3] = fmaxf(t1[h*4+3], acc[3]);
        }
    };

    // ---- LDS double-buffered stream ----
    const char*  msrc = (const char*)mem + (size_t)bid * 8192 + off0;
    const size_t step = (size_t)nb * 8192;

    gload_lds16(msrc,        lds_d0[0]);
    gload_lds16(msrc + 4096, lds_d1[0]);
    msrc += step;

    int t = bid, cur = 0;
    for (;;) {
        __syncthreads();                  // drains vmcnt: buf[cur] complete everywhere
        const bool more = (t + nb) < ntiles;
        if (more) {
            gload_lds16(msrc,        lds_d0[cur ^ 1]);
            gload_lds16(msrc + 4096, lds_d1[cur ^ 1]);
            msrc += step;
        }
        process(smem + cur * 2048);
        if (!more) break;
        __syncthreads();                  // readers of buf[cur] done before overwrite
        cur ^= 1; t += nb;
    }

    // ---- block-level merge (ltop overlays the staging LDS) ----
    __syncthreads();                      // all waves done reading staging
    float (*ltop)[65] = (float (*)[65])smem;   // [query][stream=w*16+c]

    const int col = wave * 16 + c;
    #pragma unroll
    for (int h = 0; h < 4; ++h) {
        #pragma unroll
        for (int r = 0; r < 4; ++r)
            ltop[h * 16 + g * 4 + r][col] = t1[h * 4 + r];
    }

    #pragma unroll
    for (int r = 0; r < 8; ++r) {
        float v = cs[r];
        v += __shfl_xor(v, 1, 64);
        v += __shfl_xor(v, 2, 64);
        v += __shfl_xor(v, 4, 64);
        v += __shfl_xor(v, 8, 64);
        cs[r] = v;
    }
    float ssv = sumsq;
    ssv += __shfl_xor(ssv, 1, 64);
    ssv += __shfl_xor(ssv, 2, 64);
    ssv += __shfl_xor(ssv, 4, 64);
    ssv += __shfl_xor(ssv, 8, 64);
    ssv += __shfl_xor(ssv, 16, 64);
    ssv += __shfl_xor(ssv, 32, 64);
    if (c == 0) {
        #pragma unroll
        for (int r = 0; r < 8; ++r) red[wave][g][r] = cs[r];
    }
    if (lane == 0) ssred[wave] = ssv;
    __syncthreads();

    if (tid < 32) {
        float a = red[0][tid >> 3][tid & 7] + red[1][tid >> 3][tid & 7]
                + red[2][tid >> 3][tid & 7] + red[3][tid >> 3][tid & 7];
        part_sums[(size_t)tid * nb + bid] = a;
    } else if (tid == 32) {
        part_sums[(size_t)32 * nb + bid] = ssred[0] + ssred[1] + ssred[2] + ssred[3];
    }

    if (tid < 64) {
        float lst[10];
        #pragma unroll
        for (int i = 0; i < 10; ++i) lst[i] = -FLT_MAX;
        #pragma unroll 4
        for (int s2 = 0; s2 < 64; ++s2) top10_insert(lst, ltop[tid][s2]);
        #pragma unroll
        for (int i = 0; i < 10; ++i)
            part_top[((size_t)tid * nb + bid) * 10 + i] = lst[i];
    }
}

// ---------------------------------------------------------------------------
// Kernel 2 (fused tail): 64 blocks, one per query.
// ---------------------------------------------------------------------------
__global__ __launch_bounds__(256) void ep_tail(
    const float* __restrict__ q, const float* __restrict__ part_top,
    const float* __restrict__ part_sums, float* __restrict__ out,
    int nb, int Mrows)
{
    const int b    = blockIdx.x;
    const int tid  = threadIdx.x;
    const int lane = tid & 63;
    const int wave = tid >> 6;

    __shared__ float smem[256 * 33];
    __shared__ float colsum_a[33];
    __shared__ float w4[4];
    __shared__ float mean_s, q2_s;

    if (tid < 64) {
        float x = (tid < 32) ? q[b * 32 + tid] : 0.f;
        float a = x * x;
        a += __shfl_xor(a, 1, 64);
        a += __shfl_xor(a, 2, 64);
        a += __shfl_xor(a, 4, 64);
        a += __shfl_xor(a, 8, 64);
        a += __shfl_xor(a, 16, 64);
        if (tid == 0) q2_s = a;
    }

    float a2 = 0.f;
    #pragma unroll
    for (int e = 0; e < 8; ++e) {
        float x = q[tid * 8 + e];
        a2 = fmaf(x, x, a2);
    }
    a2 += __shfl_xor(a2, 1, 64);
    a2 += __shfl_xor(a2, 2, 64);
    a2 += __shfl_xor(a2, 4, 64);
    a2 += __shfl_xor(a2, 8, 64);
    a2 += __shfl_xor(a2, 16, 64);
    a2 += __shfl_xor(a2, 32, 64);
    if (lane == 0) w4[wave] = a2;

    float acc[33];
    #pragma unroll
    for (int c2 = 0; c2 < 33; ++c2) acc[c2] = 0.f;
    for (int i = tid; i < nb; i += 256) {
        #pragma unroll
        for (int c2 = 0; c2 < 33; ++c2) acc[c2] += part_sums[(size_t)c2 * nb + i];
    }
    #pragma unroll
    for (int c2 = 0; c2 < 33; ++c2) smem[tid * 33 + c2] = acc[c2];
    __syncthreads();
    if (tid < 33) {
        float a = 0.f;
        #pragma unroll 16
        for (int j = 0; j < 256; ++j) a += smem[j * 33 + tid];
        colsum_a[tid] = a;
    }
    __syncthreads();

    if (tid < 32) {
        float qs = 0.f;
        #pragma unroll 8
        for (int bb = 0; bb < 64; ++bb) qs += q[bb * 32 + tid];
        float dq = qs * colsum_a[tid];
        dq += __shfl_xor(dq, 1, 64);
        dq += __shfl_xor(dq, 2, 64);
        dq += __shfl_xor(dq, 4, 64);
        dq += __shfl_xor(dq, 8, 64);
        dq += __shfl_xor(dq, 16, 64);
        if (tid == 0) {
            double q2sum = (double)w4[0] + (double)w4[1] + (double)w4[2] + (double)w4[3];
            double sumsq = (double)colsum_a[32];
            double Md    = (double)Mrows;
            mean_s = (float)((Md * q2sum + 64.0 * sumsq - 2.0 * (double)dq) / (64.0 * Md));
        }
    }
    __syncthreads();

    float lst[10];
    #pragma unroll
    for (int i = 0; i < 10; ++i) lst[i] = -FLT_MAX;
    const float* pt = part_top + (size_t)b * nb * 10;
    for (int i = tid; i < nb; i += 256) {
        const float* pp = pt + (size_t)i * 10;
        #pragma unroll
        for (int r = 0; r < 10; ++r) top10_insert(lst, pp[r]);
    }
    #pragma unroll
    for (int r = 0; r < 10; ++r) smem[tid * 10 + r] = lst[r];
    __syncthreads();

    if (tid < 32) {
        float m[10];
        #pragma unroll
        for (int i = 0; i < 10; ++i) m[i] = -FLT_MAX;
        for (int j2 = 0; j2 < 8; ++j2) {
            #pragma unroll
            for (int r = 0; r < 10; ++r) top10_insert(m, smem[(tid * 8 + j2) * 10 + r]);
        }
        #pragma unroll
        for (int r = 0; r < 10; ++r) smem[2560 + tid * 10 + r] = m[r];
    }
    __syncthreads();

    if (tid == 0) {
        float m[10];
        #pragma unroll
        for (int i = 0; i < 10; ++i) m[i] = -FLT_MAX;
        for (int j2 = 0; j2 < 32; ++j2) {
            #pragma unroll
            for (int r = 0; r < 10; ++r) top10_insert(m, smem[2560 + j2 * 10 + r]);
        }
        const float mean = mean_s;
        const float q2b  = q2_s;
        float sum = 0.f;
        #pragma unroll
        for (int r = 0; r < 10; ++r) {
            float sq = m[r] + q2b;
            sq = fmaxf(sq, 0.f);
            sum += KEPS / (sq / mean + KEPS);
        }
        out[b] = 1.0f / sqrtf(sum + DENOMC);
    }
}

// ---------------------------------------------------------------------------
extern "C" void kernel_launch(void* const* d_in, const int* in_sizes, int n_in,
                              void* d_out, int out_size, void* d_ws, size_t ws_size,
                              hipStream_t stream)
{
    const float* q   = (const float*)d_in[0];
    const float* mem = (const float*)d_in[1];
    float* out = (float*)d_out;

    const int Mrows  = in_sizes[1] / 32;   // 2,000,000
    const int ntiles = Mrows / 64;         // 31,250

    int nb = 1280;                         // 256 CUs x 5 resident blocks
    while (nb > 64 && ((size_t)nb * 673 + 64) * sizeof(float) > ws_size) nb >>= 1;
    if (nb > ntiles) nb = ntiles;

    float* part_top  = (float*)d_ws;                         // [64][nb][10]
    float* part_sums = part_top + (size_t)64 * nb * 10;      // [33][nb]

    ep_main<<<dim3(nb), dim3(256), 0, stream>>>(q, mem, part_top, part_sums, nb, ntiles);
    ep_tail<<<dim3(64), dim3(256), 0, stream>>>(q, part_top, part_sums, out, nb, Mrows);
}